// Round 23
// baseline (178.260 us; speedup 1.0000x reference)
//
#include <hip/hip_runtime.h>
#include <hip/hip_bf16.h>

#define EMB 1024
#define HS 64
#define SEQ 4096

using bf16x8 = __attribute__((ext_vector_type(8))) __bf16;
using f32x4  = __attribute__((ext_vector_type(4))) float;
using f32x16 = __attribute__((ext_vector_type(16))) float;

__device__ __forceinline__ ushort f2b(float f) {
    unsigned x = __float_as_uint(f);
    return (ushort)((x + 0x7fffu + ((x >> 16) & 1u)) >> 16);
}

// ---------------- Kernel A: Wq|Wk|Wv fp32 -> bf16 concat [192][1024] (R1 green) -----
__global__ void cvt_w(const float* __restrict__ wq, const float* __restrict__ wk,
                      const float* __restrict__ wv, ushort* __restrict__ wcat) {
    int i = blockIdx.x * 256 + threadIdx.x;
    const int n = HS * EMB;  // 65536
    if (i >= 3 * n) return;
    float f;
    if (i < n)          f = wq[i];
    else if (i < 2 * n) f = wk[i - n];
    else                f = wv[i - 2 * n];
    wcat[i] = f2b(f);
}

// ---------------- Kernel B: QKV projection v7 (barrier-free, direct operands) -------
// qkv was pinned at ~75us across 6 LDS+barrier variants with every pipe idle. v7
// removes ALL shared state: no LDS, no barriers, no atomics (race-free by
// construction). Wave = 16 rows x 96 cols (nt half); 4096 waves = 1024 blocks, all
// co-resident at VGPR<=128 (launch_bounds 256,4 -> 16 waves/CU). Per K-chunk of 32:
// X 8xf32 -> cvt_pk -> A-frag in registers; B-frags read directly from L2-resident
// wcat; 6 MFMA. 32 independent chunk iterations give the compiler load-ahead depth.
__global__ __launch_bounds__(256, 4) void qkv_proj(
        const float* __restrict__ x, const ushort* __restrict__ wcat,
        ushort* __restrict__ qo, ushort* __restrict__ ko, ushort* __restrict__ vo) {
    const int t = threadIdx.x;
    const int lane = t & 63, w = t >> 6;
    const int g = lane >> 4, c = lane & 15;
    const int wid = blockIdx.x * 4 + w;        // 0..4095
    const int row0 = (wid >> 1) * 16;          // 16-row group
    const int nh = wid & 1;                    // output-col half: nh*96 .. +96

    f32x4 acc[6];
#pragma unroll
    for (int i = 0; i < 6; ++i) acc[i] = f32x4{0.f, 0.f, 0.f, 0.f};

    const float* xr = x + (size_t)(row0 + c) * EMB;   // this lane's X row
    const size_t wrow0 = (size_t)(nh * 96 + c) * EMB; // this lane's first W row

#pragma unroll 2
    for (int kk = 0; kk < 32; ++kk) {
        const int k0 = kk * 32 + 8 * g;
        // A-frag: X[row0+c][k0..k0+8) fp32 -> bf16x8 (cvt_pk order validated R15)
        float4 xa = *reinterpret_cast<const float4*>(&xr[k0]);
        float4 xb = *reinterpret_cast<const float4*>(&xr[k0 + 4]);
        uint pw[4];
        asm("v_cvt_pk_bf16_f32 %0, %1, %2" : "=v"(pw[0]) : "v"(xa.x), "v"(xa.y));
        asm("v_cvt_pk_bf16_f32 %0, %1, %2" : "=v"(pw[1]) : "v"(xa.z), "v"(xa.w));
        asm("v_cvt_pk_bf16_f32 %0, %1, %2" : "=v"(pw[2]) : "v"(xb.x), "v"(xb.y));
        asm("v_cvt_pk_bf16_f32 %0, %1, %2" : "=v"(pw[3]) : "v"(xb.z), "v"(xb.w));
        bf16x8 a = *reinterpret_cast<bf16x8*>(pw);

#pragma unroll
        for (int nt = 0; nt < 6; ++nt) {
            bf16x8 b = *reinterpret_cast<const bf16x8*>(&wcat[wrow0 + (size_t)nt * 16 * EMB + k0]);
            acc[nt] = __builtin_amdgcn_mfma_f32_16x16x32_bf16(a, b, acc[nt], 0, 0, 0);
        }
    }

    const float qs = 0.125f * 1.44269504f;
#pragma unroll
    for (int nt = 0; nt < 6; ++nt) {
        int col = (nh * 6 + nt) * 16 + c;
        int rowb = row0 + 4 * g;               // C/D: row = 4g + r, col = c
        if (col < 64) {
#pragma unroll
            for (int r = 0; r < 4; ++r)
                qo[(rowb + r) * 64 + col] = f2b(acc[nt][r] * qs);
        } else if (col < 128) {
#pragma unroll
            for (int r = 0; r < 4; ++r)
                ko[(rowb + r) * 64 + (col - 64)] = f2b(acc[nt][r]);
        } else {
            int b = rowb >> 12, s0 = rowb & 4095;
            ushort4 pv;
            pv.x = f2b(acc[nt][0]); pv.y = f2b(acc[nt][1]);
            pv.z = f2b(acc[nt][2]); pv.w = f2b(acc[nt][3]);
            *reinterpret_cast<ushort4*>(&vo[(b * 64 + (col - 128)) * SEQ + s0]) = pv;
        }
    }
}

// ---------------- Kernel C: causal flash attention (kt2-loop, green x8) -------------
__global__ __launch_bounds__(256) void attn(
        const ushort* __restrict__ q, const ushort* __restrict__ k,
        const ushort* __restrict__ vt, float* __restrict__ out, float* __restrict__ L) {
    __shared__ __align__(16) char smem[32768];   // 2 x (K 8KB + V 8KB)

    const int t = threadIdx.x;
    const int lane = t & 63, w = t >> 6;
    const int ql = lane & 31, h = lane >> 5;

    // ---- block decode: (batch, qt in 0..31, seg), longest qt first ----
    const int batch = blockIdx.x & 7;
    const int x = 143 - (int)(blockIdx.x >> 3);
    int gi = 0;
#pragma unroll
    for (int g2 = 1; g2 <= 7; ++g2) if (x >= 2 * g2 * (g2 + 1)) gi = g2;
    const int off = x - 2 * gi * (gi + 1);
    const int ns = gi + 1;                 // segments per q-tile in this group
    const int j = off / ns;
    const int seg = off - j * ns;
    const int qt = 4 * gi + j;
    const int T = 2 * (qt + 1);            // causal kv range in 64-kv tiles
    const int Td = T / ns, Tr = T % ns;
    const int t0 = seg * Td + (seg < Tr ? seg : Tr);
    const int tcnt = Td + (seg < Tr ? 1 : 0);   // 2..8 tiles

    const int q0w = qt * 128 + w * 32;     // this wave's 32 q-rows

    const ushort* qb = q + (size_t)batch * SEQ * 64;
    const ushort* kb = k + (size_t)batch * SEQ * 64;
    const ushort* vb = vt + (size_t)batch * 64 * SEQ;

    // Q fragments (B-operand, 16x32 per kstep): lane: col q=ql, k=8h+j
    bf16x8 qa[4];
#pragma unroll
    for (int ks = 0; ks < 4; ++ks)
        qa[ks] = *reinterpret_cast<const bf16x8*>(&qb[(q0w + ql) * 64 + ks * 16 + 8 * h]);

    f32x16 accO0, accO1;
#pragma unroll
    for (int r = 0; r < 16; ++r) { accO0[r] = 0.f; accO1[r] = 0.f; }
    float lsum = 0.f;

    // fragment-major staging: 16 frags x 1KB per tile (K: kt2*4+ks, V: 8+nt2*4+kk2)
    auto stage = [&](int tile, int buf) {
        const int kv0 = tile * 64;
#pragma unroll
        for (int n = 0; n < 4; ++n) {
            const int fid = w * 4 + n;
            const ushort* src;
            if (fid < 8)
                src = &kb[(size_t)(kv0 + (fid >> 2) * 32 + ql) * 64 + (fid & 3) * 16 + 8 * h];
            else
                src = &vb[(size_t)(((fid - 8) >> 2) * 32 + ql) * SEQ + kv0 + ((fid - 8) & 3) * 16 + 8 * h];
            char* dst = smem + buf * 16384 + fid * 1024 + lane * 16;
            __builtin_amdgcn_global_load_lds(
                (const __attribute__((address_space(1))) void*)src,
                (__attribute__((address_space(3))) void*)dst, 16, 0, 0);
        }
    };

    stage(t0, 0);

    for (int ti = 0; ti < tcnt; ++ti) {
        asm volatile("s_waitcnt vmcnt(0)" ::: "memory");
        __builtin_amdgcn_s_barrier();
        __builtin_amdgcn_sched_barrier(0);
        if (ti + 1 < tcnt) stage(t0 + ti + 1, (ti + 1) & 1);

        const char* kbase = smem + (ti & 1) * 16384;
        const char* vbase = kbase + 8192;
        const int kv0 = (t0 + ti) * 64;
        const bool cross = (kv0 + 64 > q0w);   // any masking needed for this wave

#pragma unroll
        for (int kt2 = 0; kt2 < 2; ++kt2) {
            // ---- QK^T (swapped): S[kv=kt2*32+..][q], q=ql, kv from reg ----
            f32x16 S;
#pragma unroll
            for (int r = 0; r < 16; ++r) S[r] = 0.f;
#pragma unroll
            for (int ks = 0; ks < 4; ++ks) {
                bf16x8 kf = *reinterpret_cast<const bf16x8*>(kbase + (kt2 * 4 + ks) * 1024 + lane * 16);
                S = __builtin_amdgcn_mfma_f32_32x32x16_bf16(kf, qa[ks], S, 0, 0, 0);
            }
            if (cross) {
#pragma unroll
                for (int r = 0; r < 16; ++r) {
                    int kv = kv0 + kt2 * 32 + (r & 3) + 8 * (r >> 2) + 4 * h;
                    if (kv > q0w + ql) S[r] = -INFINITY;
                }
            }
            // ---- softmax (no max) + pack P to bf16 dwords ----
            uint d0, d1, d2, d3, d4, d5, d6, d7;
            {
                float p[16];
#pragma unroll
                for (int r = 0; r < 16; ++r) {
                    p[r] = __builtin_amdgcn_exp2f(S[r]);
                    lsum += p[r];
                }
                asm("v_cvt_pk_bf16_f32 %0, %1, %2" : "=v"(d0) : "v"(p[0]),  "v"(p[1]));
                asm("v_cvt_pk_bf16_f32 %0, %1, %2" : "=v"(d1) : "v"(p[2]),  "v"(p[3]));
                asm("v_cvt_pk_bf16_f32 %0, %1, %2" : "=v"(d2) : "v"(p[4]),  "v"(p[5]));
                asm("v_cvt_pk_bf16_f32 %0, %1, %2" : "=v"(d3) : "v"(p[6]),  "v"(p[7]));
                asm("v_cvt_pk_bf16_f32 %0, %1, %2" : "=v"(d4) : "v"(p[8]),  "v"(p[9]));
                asm("v_cvt_pk_bf16_f32 %0, %1, %2" : "=v"(d5) : "v"(p[10]), "v"(p[11]));
                asm("v_cvt_pk_bf16_f32 %0, %1, %2" : "=v"(d6) : "v"(p[12]), "v"(p[13]));
                asm("v_cvt_pk_bf16_f32 %0, %1, %2" : "=v"(d7) : "v"(p[14]), "v"(p[15]));
            }
            // ---- P -> A-frag via permlane32_swap; PV ----
#pragma unroll
            for (int kk = 0; kk < 2; ++kk) {
                uint a0 = kk ? d4 : d0, a1 = kk ? d5 : d1;
                uint b0 = kk ? d6 : d2, b1 = kk ? d7 : d3;
                asm("v_permlane32_swap_b32 %0, %1" : "+v"(a0), "+v"(b0));
                asm("v_permlane32_swap_b32 %0, %1" : "+v"(a1), "+v"(b1));
                uint pw[4] = {a0, a1, b0, b1};
                bf16x8 pa = *reinterpret_cast<bf16x8*>(pw);
                const int kk2 = kt2 * 2 + kk;
                bf16x8 vf0 = *reinterpret_cast<const bf16x8*>(vbase + (0 * 4 + kk2) * 1024 + lane * 16);
                bf16x8 vf1 = *reinterpret_cast<const bf16x8*>(vbase + (1 * 4 + kk2) * 1024 + lane * 16);
                accO0 = __builtin_amdgcn_mfma_f32_32x32x16_bf16(pa, vf0, accO0, 0, 0, 0);
                accO1 = __builtin_amdgcn_mfma_f32_32x32x16_bf16(pa, vf1, accO1, 0, 0, 0);
            }
        }
    }

    // ---- flush: l across halves, then atomic merge ----
    lsum += __shfl_xor(lsum, 32, 64);
    float* ob = out + (size_t)batch * SEQ * 64;
#pragma unroll
    for (int r = 0; r < 16; ++r) {
        int qrow = q0w + (r & 3) + 8 * (r >> 2) + 4 * h;
        atomicAdd(&ob[(size_t)qrow * 64 + ql], accO0[r]);
        atomicAdd(&ob[(size_t)qrow * 64 + 32 + ql], accO1[r]);
    }
    if (h == 0) atomicAdd(&L[batch * SEQ + q0w + ql], lsum);
}

// ---------------- Kernel D: normalize out /= L (guarded; validated) -----------------
__global__ __launch_bounds__(256) void norm_out(float* __restrict__ out,
                                                const float* __restrict__ L) {
    int i = blockIdx.x * 256 + threadIdx.x;     // one float4 per thread; 16 per row
    float4 v = reinterpret_cast<float4*>(out)[i];
    float li = L[i >> 4];
    float inv = (li > 0.f) ? 1.0f / li : 0.f;
    v.x *= inv; v.y *= inv; v.z *= inv; v.w *= inv;
    reinterpret_cast<float4*>(out)[i] = v;
}

extern "C" void kernel_launch(void* const* d_in, const int* in_sizes, int n_in,
                              void* d_out, int out_size, void* d_ws, size_t ws_size,
                              hipStream_t stream) {
    const float* x  = (const float*)d_in[0];
    const float* wq = (const float*)d_in[1];
    const float* wk = (const float*)d_in[2];
    const float* wv = (const float*)d_in[3];
    float* out = (float*)d_out;

    char* ws = (char*)d_ws;
    ushort* wcat = (ushort*)ws;                              // 384 KiB
    ushort* qo   = (ushort*)(ws + 393216);                   // 4 MB
    ushort* ko   = (ushort*)(ws + 393216 + 4194304);         // 4 MB
    ushort* vo   = (ushort*)(ws + 393216 + 2 * 4194304);     // 4 MB (V^T [b][64][s])
    float*  Lb   = (float*)(ws + 393216 + 3 * 4194304);      // 128 KiB

    hipMemsetAsync(out, 0, (size_t)8 * SEQ * 64 * 4, stream);
    hipMemsetAsync(Lb, 0, (size_t)8 * SEQ * 4, stream);
    hipLaunchKernelGGL(cvt_w, dim3(768), dim3(256), 0, stream, wq, wk, wv, wcat);
    hipLaunchKernelGGL(qkv_proj, dim3(1024), dim3(256), 0, stream, x, wcat, qo, ko, vo);
    hipLaunchKernelGGL(attn, dim3(1152), dim3(256), 0, stream, qo, ko, vo, out, Lb);
    hipLaunchKernelGGL(norm_out, dim3(2048), dim3(256), 0, stream, out, Lb);
}

// Round 24
// 92.855 us; speedup vs baseline: 1.9198x; 1.9198x over previous
//
#include <hip/hip_runtime.h>
#include <hip/hip_bf16.h>

#define EMB 1024
#define HS 64
#define SEQ 4096

using bf16x8 = __attribute__((ext_vector_type(8))) __bf16;
using f32x4  = __attribute__((ext_vector_type(4))) float;
using f32x16 = __attribute__((ext_vector_type(16))) float;

__device__ __forceinline__ ushort f2b(float f) {
    unsigned x = __float_as_uint(f);
    return (ushort)((x + 0x7fffu + ((x >> 16) & 1u)) >> 16);
}

// ---------------- Kernel A: Wq|Wk|Wv fp32 -> bf16 concat [192][1024] (R1 green) -----
__global__ void cvt_w(const float* __restrict__ wq, const float* __restrict__ wk,
                      const float* __restrict__ wv, ushort* __restrict__ wcat) {
    int i = blockIdx.x * 256 + threadIdx.x;
    const int n = HS * EMB;  // 65536
    if (i >= 3 * n) return;
    float f;
    if (i < n)          f = wq[i];
    else if (i < 2 * n) f = wk[i - n];
    else                f = wv[i - 2 * n];
    wcat[i] = f2b(f);
}

// ---------------- Kernel B: QKV projection v5 (K-chunk 128; R20/R22 green) ----------
// R1/R14-green single-buffer structure, K=128 per stage (8 chunks, 8 barrier-pairs).
// 512 blocks x 1024 thr (16 waves), M=64 rows. LDS: X[64][136] + W[192][136] = 70KB.
__global__ __launch_bounds__(1024) void qkv_proj(
        const float* __restrict__ x, const ushort* __restrict__ wcat,
        ushort* __restrict__ qo, ushort* __restrict__ ko, ushort* __restrict__ vo) {
    __shared__ ushort Xs[64][136];    // 128 cols + 8 pad
    __shared__ ushort Ws[192][136];
    const int t = threadIdx.x;
    const int lane = t & 63, wid = t >> 6;
    const int g = lane >> 4, c = lane & 15;
    const int strip = wid >> 2, colq = wid & 3;
    const int row0 = blockIdx.x * 64;

    f32x4 acc[3];
#pragma unroll
    for (int i = 0; i < 3; ++i) acc[i] = f32x4{0.f, 0.f, 0.f, 0.f};

    for (int kc = 0; kc < EMB; kc += 128) {
        __syncthreads();
#pragma unroll
        for (int p = 0; p < 2; ++p) {   // stage X tile 64x128 f32 -> bf16 (2 float4/thr)
            int r = p * 32 + (t >> 5), cc = (t & 31) * 4;
            float4 v = *reinterpret_cast<const float4*>(&x[(size_t)(row0 + r) * EMB + kc + cc]);
            ushort4 u;
            u.x = f2b(v.x); u.y = f2b(v.y); u.z = f2b(v.z); u.w = f2b(v.w);
            *reinterpret_cast<ushort4*>(&Xs[r][cc]) = u;
        }
#pragma unroll
        for (int i = 0; i < 6; ++i) {   // stage W tile 192x128 bf16 (6 ushort4/thr)
            int wr = i * 32 + (t >> 5), wc = (t & 31) * 4;
            *reinterpret_cast<ushort4*>(&Ws[wr][wc]) =
                *reinterpret_cast<const ushort4*>(&wcat[(size_t)wr * EMB + kc + wc]);
        }
        __syncthreads();
#pragma unroll
        for (int kk = 0; kk < 4; ++kk) {
            bf16x8 a = *reinterpret_cast<const bf16x8*>(&Xs[strip * 16 + c][kk * 32 + 8 * g]);
#pragma unroll
            for (int nt = 0; nt < 3; ++nt) {
                bf16x8 b = *reinterpret_cast<const bf16x8*>(
                    &Ws[(colq * 3 + nt) * 16 + c][kk * 32 + 8 * g]);
                acc[nt] = __builtin_amdgcn_mfma_f32_16x16x32_bf16(a, b, acc[nt], 0, 0, 0);
            }
        }
    }

    const float qs = 0.125f * 1.44269504f;
#pragma unroll
    for (int nt = 0; nt < 3; ++nt) {
        int col = (colq * 3 + nt) * 16 + c;
        int rowb = row0 + strip * 16 + 4 * g;
        if (col < 64) {
#pragma unroll
            for (int r = 0; r < 4; ++r)
                qo[(rowb + r) * 64 + col] = f2b(acc[nt][r] * qs);
        } else if (col < 128) {
#pragma unroll
            for (int r = 0; r < 4; ++r)
                ko[(rowb + r) * 64 + (col - 64)] = f2b(acc[nt][r]);
        } else {
            int b = rowb >> 12, s0 = rowb & 4095;
            ushort4 pv;
            pv.x = f2b(acc[nt][0]); pv.y = f2b(acc[nt][1]);
            pv.z = f2b(acc[nt][2]); pv.w = f2b(acc[nt][3]);
            *reinterpret_cast<ushort4*>(&vo[(b * 64 + (col - 128)) * SEQ + s0]) = pv;
        }
    }
}

// ---------------- Kernel C: causal flash attention (kt2-loop, green x8) -------------
__global__ __launch_bounds__(256) void attn(
        const ushort* __restrict__ q, const ushort* __restrict__ k,
        const ushort* __restrict__ vt, float* __restrict__ out, float* __restrict__ L) {
    __shared__ __align__(16) char smem[32768];   // 2 x (K 8KB + V 8KB)

    const int t = threadIdx.x;
    const int lane = t & 63, w = t >> 6;
    const int ql = lane & 31, h = lane >> 5;

    // ---- block decode: (batch, qt in 0..31, seg), longest qt first ----
    const int batch = blockIdx.x & 7;
    const int x = 143 - (int)(blockIdx.x >> 3);
    int gi = 0;
#pragma unroll
    for (int g2 = 1; g2 <= 7; ++g2) if (x >= 2 * g2 * (g2 + 1)) gi = g2;
    const int off = x - 2 * gi * (gi + 1);
    const int ns = gi + 1;                 // segments per q-tile in this group
    const int j = off / ns;
    const int seg = off - j * ns;
    const int qt = 4 * gi + j;
    const int T = 2 * (qt + 1);            // causal kv range in 64-kv tiles
    const int Td = T / ns, Tr = T % ns;
    const int t0 = seg * Td + (seg < Tr ? seg : Tr);
    const int tcnt = Td + (seg < Tr ? 1 : 0);   // 2..8 tiles

    const int q0w = qt * 128 + w * 32;     // this wave's 32 q-rows

    const ushort* qb = q + (size_t)batch * SEQ * 64;
    const ushort* kb = k + (size_t)batch * SEQ * 64;
    const ushort* vb = vt + (size_t)batch * 64 * SEQ;

    // Q fragments (B-operand, 16x32 per kstep): lane: col q=ql, k=8h+j
    bf16x8 qa[4];
#pragma unroll
    for (int ks = 0; ks < 4; ++ks)
        qa[ks] = *reinterpret_cast<const bf16x8*>(&qb[(q0w + ql) * 64 + ks * 16 + 8 * h]);

    f32x16 accO0, accO1;
#pragma unroll
    for (int r = 0; r < 16; ++r) { accO0[r] = 0.f; accO1[r] = 0.f; }
    float lsum = 0.f;

    // fragment-major staging: 16 frags x 1KB per tile (K: kt2*4+ks, V: 8+nt2*4+kk2)
    auto stage = [&](int tile, int buf) {
        const int kv0 = tile * 64;
#pragma unroll
        for (int n = 0; n < 4; ++n) {
            const int fid = w * 4 + n;
            const ushort* src;
            if (fid < 8)
                src = &kb[(size_t)(kv0 + (fid >> 2) * 32 + ql) * 64 + (fid & 3) * 16 + 8 * h];
            else
                src = &vb[(size_t)(((fid - 8) >> 2) * 32 + ql) * SEQ + kv0 + ((fid - 8) & 3) * 16 + 8 * h];
            char* dst = smem + buf * 16384 + fid * 1024 + lane * 16;
            __builtin_amdgcn_global_load_lds(
                (const __attribute__((address_space(1))) void*)src,
                (__attribute__((address_space(3))) void*)dst, 16, 0, 0);
        }
    };

    stage(t0, 0);

    for (int ti = 0; ti < tcnt; ++ti) {
        asm volatile("s_waitcnt vmcnt(0)" ::: "memory");
        __builtin_amdgcn_s_barrier();
        __builtin_amdgcn_sched_barrier(0);
        if (ti + 1 < tcnt) stage(t0 + ti + 1, (ti + 1) & 1);

        const char* kbase = smem + (ti & 1) * 16384;
        const char* vbase = kbase + 8192;
        const int kv0 = (t0 + ti) * 64;
        const bool cross = (kv0 + 64 > q0w);   // any masking needed for this wave

#pragma unroll
        for (int kt2 = 0; kt2 < 2; ++kt2) {
            // ---- QK^T (swapped): S[kv=kt2*32+..][q], q=ql, kv from reg ----
            f32x16 S;
#pragma unroll
            for (int r = 0; r < 16; ++r) S[r] = 0.f;
#pragma unroll
            for (int ks = 0; ks < 4; ++ks) {
                bf16x8 kf = *reinterpret_cast<const bf16x8*>(kbase + (kt2 * 4 + ks) * 1024 + lane * 16);
                S = __builtin_amdgcn_mfma_f32_32x32x16_bf16(kf, qa[ks], S, 0, 0, 0);
            }
            if (cross) {
#pragma unroll
                for (int r = 0; r < 16; ++r) {
                    int kv = kv0 + kt2 * 32 + (r & 3) + 8 * (r >> 2) + 4 * h;
                    if (kv > q0w + ql) S[r] = -INFINITY;
                }
            }
            // ---- softmax (no max) + pack P to bf16 dwords ----
            uint d0, d1, d2, d3, d4, d5, d6, d7;
            {
                float p[16];
#pragma unroll
                for (int r = 0; r < 16; ++r) {
                    p[r] = __builtin_amdgcn_exp2f(S[r]);
                    lsum += p[r];
                }
                asm("v_cvt_pk_bf16_f32 %0, %1, %2" : "=v"(d0) : "v"(p[0]),  "v"(p[1]));
                asm("v_cvt_pk_bf16_f32 %0, %1, %2" : "=v"(d1) : "v"(p[2]),  "v"(p[3]));
                asm("v_cvt_pk_bf16_f32 %0, %1, %2" : "=v"(d2) : "v"(p[4]),  "v"(p[5]));
                asm("v_cvt_pk_bf16_f32 %0, %1, %2" : "=v"(d3) : "v"(p[6]),  "v"(p[7]));
                asm("v_cvt_pk_bf16_f32 %0, %1, %2" : "=v"(d4) : "v"(p[8]),  "v"(p[9]));
                asm("v_cvt_pk_bf16_f32 %0, %1, %2" : "=v"(d5) : "v"(p[10]), "v"(p[11]));
                asm("v_cvt_pk_bf16_f32 %0, %1, %2" : "=v"(d6) : "v"(p[12]), "v"(p[13]));
                asm("v_cvt_pk_bf16_f32 %0, %1, %2" : "=v"(d7) : "v"(p[14]), "v"(p[15]));
            }
            // ---- P -> A-frag via permlane32_swap; PV ----
#pragma unroll
            for (int kk = 0; kk < 2; ++kk) {
                uint a0 = kk ? d4 : d0, a1 = kk ? d5 : d1;
                uint b0 = kk ? d6 : d2, b1 = kk ? d7 : d3;
                asm("v_permlane32_swap_b32 %0, %1" : "+v"(a0), "+v"(b0));
                asm("v_permlane32_swap_b32 %0, %1" : "+v"(a1), "+v"(b1));
                uint pw[4] = {a0, a1, b0, b1};
                bf16x8 pa = *reinterpret_cast<bf16x8*>(pw);
                const int kk2 = kt2 * 2 + kk;
                bf16x8 vf0 = *reinterpret_cast<const bf16x8*>(vbase + (0 * 4 + kk2) * 1024 + lane * 16);
                bf16x8 vf1 = *reinterpret_cast<const bf16x8*>(vbase + (1 * 4 + kk2) * 1024 + lane * 16);
                accO0 = __builtin_amdgcn_mfma_f32_32x32x16_bf16(pa, vf0, accO0, 0, 0, 0);
                accO1 = __builtin_amdgcn_mfma_f32_32x32x16_bf16(pa, vf1, accO1, 0, 0, 0);
            }
        }
    }

    // ---- flush: l across halves, then atomic merge ----
    lsum += __shfl_xor(lsum, 32, 64);
    float* ob = out + (size_t)batch * SEQ * 64;
#pragma unroll
    for (int r = 0; r < 16; ++r) {
        int qrow = q0w + (r & 3) + 8 * (r >> 2) + 4 * h;
        atomicAdd(&ob[(size_t)qrow * 64 + ql], accO0[r]);
        atomicAdd(&ob[(size_t)qrow * 64 + 32 + ql], accO1[r]);
    }
    if (h == 0) atomicAdd(&L[batch * SEQ + q0w + ql], lsum);
}

// ---------------- Kernel D: normalize out /= L (guarded; validated) -----------------
__global__ __launch_bounds__(256) void norm_out(float* __restrict__ out,
                                                const float* __restrict__ L) {
    int i = blockIdx.x * 256 + threadIdx.x;     // one float4 per thread; 16 per row
    float4 v = reinterpret_cast<float4*>(out)[i];
    float li = L[i >> 4];
    float inv = (li > 0.f) ? 1.0f / li : 0.f;
    v.x *= inv; v.y *= inv; v.z *= inv; v.w *= inv;
    reinterpret_cast<float4*>(out)[i] = v;
}

extern "C" void kernel_launch(void* const* d_in, const int* in_sizes, int n_in,
                              void* d_out, int out_size, void* d_ws, size_t ws_size,
                              hipStream_t stream) {
    const float* x  = (const float*)d_in[0];
    const float* wq = (const float*)d_in[1];
    const float* wk = (const float*)d_in[2];
    const float* wv = (const float*)d_in[3];
    float* out = (float*)d_out;

    char* ws = (char*)d_ws;
    ushort* wcat = (ushort*)ws;                              // 384 KiB
    ushort* qo   = (ushort*)(ws + 393216);                   // 4 MB
    ushort* ko   = (ushort*)(ws + 393216 + 4194304);         // 4 MB
    ushort* vo   = (ushort*)(ws + 393216 + 2 * 4194304);     // 4 MB (V^T [b][64][s])
    float*  Lb   = (float*)(ws + 393216 + 3 * 4194304);      // 128 KiB

    hipMemsetAsync(out, 0, (size_t)8 * SEQ * 64 * 4, stream);
    hipMemsetAsync(Lb, 0, (size_t)8 * SEQ * 4, stream);
    hipLaunchKernelGGL(cvt_w, dim3(768), dim3(256), 0, stream, wq, wk, wv, wcat);
    hipLaunchKernelGGL(qkv_proj, dim3(512), dim3(1024), 0, stream, x, wcat, qo, ko, vo);
    hipLaunchKernelGGL(attn, dim3(1152), dim3(256), 0, stream, qo, ko, vo, out, Lb);
    hipLaunchKernelGGL(norm_out, dim3(2048), dim3(256), 0, stream, out, Lb);
}